// Round 2
// baseline (2848.718 us; speedup 1.0000x reference)
//
#include <hip/hip_runtime.h>
#include <hip/hip_bf16.h>

// ---------------- problem constants (fixed by the benchmark) ----------------
#define T_TOK 8192
#define DDIM  2048
#define HDIM  8192
#define NEXP  8
#define TOPK  2
#define NENT  (T_TOK*TOPK)   // 16384 routed entries total
#define MB_TILES 32          // covers up to 4096 rows/expert (mean 2048)

typedef short bf16x8 __attribute__((ext_vector_type(8)));
typedef float f32x4  __attribute__((ext_vector_type(4)));

static __device__ __forceinline__ ushort f2bf(float f) {
    unsigned u = __float_as_uint(f);
    u += 0x7FFF + ((u >> 16) & 1);   // RNE
    return (ushort)(u >> 16);
}

static __device__ __forceinline__ float gelu_f(float x) {
    // jax.nn.gelu default: tanh approximation
    float u = 0.7978845608028654f * (x + 0.044715f * x * x * x);
    float e = __expf(2.0f * u);
    float t = 1.0f - 2.0f / (e + 1.0f);   // tanh(u), robust at +-inf
    return 0.5f * x * (1.0f + t);
}

static __device__ __forceinline__ void glds16(const void* g, void* l) {
    // async global->LDS, 16B per lane; LDS dest is wave-uniform base + lane*16
    __builtin_amdgcn_global_load_lds((const __attribute__((address_space(1))) void*)g,
                                     (__attribute__((address_space(3))) void*)l,
                                     16, 0, 0);
}

// ---------------- conversion kernels ----------------
__global__ void k_cvt_x(const float* __restrict__ x, ushort* __restrict__ xb) {
    const float4* x4 = (const float4*)x;
    ushort4* o4 = (ushort4*)xb;
    const int n4 = T_TOK * DDIM / 4;
    for (int i = blockIdx.x * blockDim.x + threadIdx.x; i < n4; i += gridDim.x * blockDim.x) {
        float4 v = x4[i];
        ushort4 u;
        u.x = f2bf(v.x); u.y = f2bf(v.y); u.z = f2bf(v.z); u.w = f2bf(v.w);
        o4[i] = u;
    }
}

// in: [E][R][C] fp32  ->  out: [E][C][R] bf16   (transpose + convert)
__global__ void k_cvt_t(const float* __restrict__ in, ushort* __restrict__ out,
                        int R, int C) {
    __shared__ float t[32][33];
    int e = blockIdx.z;
    int r0 = blockIdx.y * 32, c0 = blockIdx.x * 32;
    int tr = threadIdx.x >> 5, tc = threadIdx.x & 31;   // 8 x 32
    const float* src = in + (size_t)e * R * C;
    ushort* dst = out + (size_t)e * C * R;
#pragma unroll
    for (int p = 0; p < 4; ++p)
        t[tr + p * 8][tc] = src[(size_t)(r0 + tr + p * 8) * C + (c0 + tc)];
    __syncthreads();
#pragma unroll
    for (int p = 0; p < 4; ++p)
        dst[(size_t)(c0 + tr + p * 8) * R + (r0 + tc)] = f2bf(t[tc][tr + p * 8]);
}

// ---------------- routing ----------------
// meta layout (ints): [0..7]=cnt  [8..15]=offset  [16..23]=cursor  [24]=idx-is-int32 flag
__global__ void k_detect(const void* __restrict__ idx, int* __restrict__ meta) {
    // Read the first NENT/2 entries as int64 (64KB -- in bounds under BOTH
    // dtype interpretations). Any value outside [0,NEXP) => buffer is int32.
    const long long* p = (const long long*)idx;
    int i = blockIdx.x * 256 + threadIdx.x;
    if (i < NENT / 2) {
        long long v = p[i];
        if (v < 0 || v >= NEXP) atomicOr(&meta[24], 1);
    }
}
static __device__ __forceinline__ int load_idx(const void* idx, int i, int use32) {
    return use32 ? ((const int*)idx)[i] : (int)((const long long*)idx)[i];
}
__global__ void k_count(const void* __restrict__ idx, int* __restrict__ meta) {
    int use32 = meta[24];
    int i = blockIdx.x * 256 + threadIdx.x;
    if (i < NENT) atomicAdd(&meta[load_idx(idx, i, use32)], 1);
}
__global__ void k_offset(int* __restrict__ meta) {
    if (threadIdx.x == 0) {
        int s = 0;
        for (int e = 0; e < NEXP; ++e) { meta[8 + e] = s; meta[16 + e] = s; s += meta[e]; }
    }
}
__global__ void k_place(const void* __restrict__ idx, const float* __restrict__ p,
                        int* __restrict__ meta, int* __restrict__ tok,
                        float* __restrict__ gate) {
    int use32 = meta[24];
    int i = blockIdx.x * 256 + threadIdx.x;
    if (i < NENT) {
        int e = load_idx(idx, i, use32);
        int pos = atomicAdd(&meta[16 + e], 1);
        tok[pos] = i >> 1;      // token id (K=2)
        gate[pos] = p[i];
    }
}

// ---------------- MFMA GEMM ----------------
// MODE 0: h[ent][n] = gelu( xb[tok[ent]] . w1b[e][n] ),  K=DDIM, N=HDIM
// MODE 1: y[tok[ent]][n] += gate[ent] * ( h[ent] . w2b[e][n] ), K=HDIM, N=DDIM
// A rows and B rows are both k-contiguous (B is pre-transposed [E][N][K]).
template<int MODE>
__global__ __launch_bounds__(256, 2)
void k_gemm(const ushort* __restrict__ A, const ushort* __restrict__ B,
            const int* __restrict__ meta, const int* __restrict__ tok,
            const float* __restrict__ gate, void* __restrict__ OUT,
            int K, int N) {
    __shared__ __align__(16) ushort As[128 * 32];
    __shared__ __align__(16) ushort Bs[128 * 32];

    const int e = blockIdx.z;
    const int cnt = meta[e];
    const int rows0 = blockIdx.y * 128;
    if (rows0 >= cnt) return;
    const int off = meta[8 + e];
    const int n0 = blockIdx.x * 128;

    const int tid = threadIdx.x;
    const int l = tid & 63;
    const int w = tid >> 6;          // wave 0..3
    const int wm = w >> 1, wn = w & 1;

    // staging coords: wave w covers rows [w*32, w*32+32) in two 16-row passes
    const int seg = l & 3;                    // 16B segment within a 64B k-chunk
    const int srow0 = w * 32 + (l >> 2);      // pass 0 row
    const int srow1 = srow0 + 16;             // pass 1 row

    // A source rows (gathered for MODE0, identity for MODE1), clamped for padding
    size_t arow0, arow1;
    {
        int rl0 = rows0 + srow0, rl1 = rows0 + srow1;
        int ar0, ar1;
        if (MODE == 0) {
            ar0 = (rl0 < cnt) ? tok[off + rl0] : 0;
            ar1 = (rl1 < cnt) ? tok[off + rl1] : 0;
        } else {
            ar0 = (rl0 < cnt) ? (off + rl0) : 0;
            ar1 = (rl1 < cnt) ? (off + rl1) : 0;
        }
        arow0 = (size_t)ar0; arow1 = (size_t)ar1;
    }
    const ushort* ga0 = A + arow0 * (size_t)K + seg * 8;
    const ushort* ga1 = A + arow1 * (size_t)K + seg * 8;
    const ushort* gb0 = B + ((size_t)e * N + n0 + srow0) * (size_t)K + seg * 8;
    const ushort* gb1 = gb0 + (size_t)16 * K;

    // wave-uniform LDS staging bases
    ushort* lba0 = &As[(w * 32) * 32];
    ushort* lba1 = &As[(w * 32 + 16) * 32];
    ushort* lbb0 = &Bs[(w * 32) * 32];
    ushort* lbb1 = &Bs[(w * 32 + 16) * 32];

    f32x4 acc[4][4] = {};

    const int frow = l & 15;          // fragment row/col within 16
    const int fk = (l >> 4) * 8;      // k-offset of this lane's 8 elements

    for (int k0 = 0; k0 < K; k0 += 32) {
        __syncthreads();              // previous iter's LDS reads done
        glds16(ga0 + k0, lba0);
        glds16(ga1 + k0, lba1);
        glds16(gb0 + k0, lbb0);
        glds16(gb1 + k0, lbb1);
        __syncthreads();              // drains vmcnt + barrier

        bf16x8 a[4], b[4];
#pragma unroll
        for (int mi = 0; mi < 4; ++mi)
            a[mi] = *(const bf16x8*)&As[(wm * 64 + mi * 16 + frow) * 32 + fk];
#pragma unroll
        for (int ni = 0; ni < 4; ++ni)
            b[ni] = *(const bf16x8*)&Bs[(wn * 64 + ni * 16 + frow) * 32 + fk];
#pragma unroll
        for (int mi = 0; mi < 4; ++mi)
#pragma unroll
            for (int ni = 0; ni < 4; ++ni)
                acc[mi][ni] = __builtin_amdgcn_mfma_f32_16x16x32_bf16(
                    a[mi], b[ni], acc[mi][ni], 0, 0, 0);
    }

    // epilogue: D[row=(l>>4)*4+j][col=l&15] per 16x16 fragment
    const int colb = n0 + wn * 64 + (l & 15);
#pragma unroll
    for (int mi = 0; mi < 4; ++mi) {
#pragma unroll
        for (int j = 0; j < 4; ++j) {
            int rl = rows0 + wm * 64 + mi * 16 + (l >> 4) * 4 + j;
            if (rl < cnt) {
                int ent = off + rl;
                if (MODE == 0) {
                    ushort* hout = (ushort*)OUT;
#pragma unroll
                    for (int ni = 0; ni < 4; ++ni)
                        hout[(size_t)ent * N + colb + ni * 16] =
                            f2bf(gelu_f(acc[mi][ni][j]));
                } else {
                    float gv = gate[ent];
                    float* y = (float*)OUT + (size_t)tok[ent] * N + colb;
#pragma unroll
                    for (int ni = 0; ni < 4; ++ni)
                        atomicAdd(y + ni * 16, gv * acc[mi][ni][j]);
                }
            }
        }
    }
}

// ---------------- launcher ----------------
extern "C" void kernel_launch(void* const* d_in, const int* in_sizes, int n_in,
                              void* d_out, int out_size, void* d_ws, size_t ws_size,
                              hipStream_t stream) {
    const float* x  = (const float*)d_in[0];
    const float* ep = (const float*)d_in[1];
    const void*  ei = d_in[2];               // int32 or int64 -- detected on device
    const float* w1 = (const float*)d_in[3];
    const float* w2 = (const float*)d_in[4];
    float* y = (float*)d_out;

    // workspace layout; w2b ALIASES w1b (w1b dead after GEMM1, stream serializes)
    char* ws = (char*)d_ws;
    size_t o = 0;
    int* meta = (int*)(ws + o);      o += 4096;
    int* tok  = (int*)(ws + o);      o += (size_t)NENT * 4;
    float* gate = (float*)(ws + o);  o += (size_t)NENT * 4;
    o = (o + 255) & ~(size_t)255;
    ushort* xb  = (ushort*)(ws + o); o += (size_t)T_TOK * DDIM * 2;     // 33.5 MB
    ushort* w1b = (ushort*)(ws + o); o += (size_t)NEXP * DDIM * HDIM * 2; // 268 MB
    ushort* w2b = w1b;                                                   // aliased
    ushort* h   = (ushort*)(ws + o); o += (size_t)NENT * HDIM * 2;       // 268 MB
    if (ws_size < o) return;   // workspace too small -> validation will flag

    hipMemsetAsync(meta, 0, 128, stream);
    hipMemsetAsync(d_out, 0, (size_t)out_size * 4, stream);

    // routing (with idx dtype detection)
    k_detect<<<NENT / 512, 256, 0, stream>>>(ei, meta);
    k_count<<<NENT / 256, 256, 0, stream>>>(ei, meta);
    k_offset<<<1, 64, 0, stream>>>(meta);
    k_place<<<NENT / 256, 256, 0, stream>>>(ei, ep, meta, tok, gate);

    // convert x and w1, run GEMM1
    k_cvt_x<<<2048, 256, 0, stream>>>(x, xb);
    dim3 gt1(HDIM / 32, DDIM / 32, NEXP);
    k_cvt_t<<<gt1, 256, 0, stream>>>(w1, w1b, DDIM, HDIM);
    dim3 gg1(HDIM / 128, MB_TILES, NEXP);
    k_gemm<0><<<gg1, 256, 0, stream>>>(xb, w1b, meta, tok, gate, h, DDIM, HDIM);

    // convert w2 into the (now dead) w1b buffer, run GEMM2
    dim3 gt2(DDIM / 32, HDIM / 32, NEXP);
    k_cvt_t<<<gt2, 256, 0, stream>>>(w2, w2b, HDIM, DDIM);
    dim3 gg2(DDIM / 128, MB_TILES, NEXP);
    k_gemm<1><<<gg2, 256, 0, stream>>>(h, w2b, meta, tok, gate, y, HDIM, DDIM);
}